// Round 6
// baseline (355.693 us; speedup 1.0000x reference)
//
#include <hip/hip_runtime.h>
#include <hip/hip_bf16.h>

// Problem constants
#define B_  4
#define S_  1024
#define H_  1024
#define NH  16
#define HD  64
#define P_  4

typedef __attribute__((ext_vector_type(8))) short bf16x8;
typedef __attribute__((ext_vector_type(4))) float f32x4;
typedef __attribute__((ext_vector_type(16))) float f32x16;
typedef __attribute__((ext_vector_type(4))) unsigned int u32x4;

__device__ __forceinline__ float b2f(short s) {
  union { unsigned int u; float f; } v;
  v.u = ((unsigned int)(unsigned short)s) << 16;
  return v.f;
}
__device__ __forceinline__ short f2b(float f) {
  __hip_bfloat16 h = __float2bfloat16(f);
  return *reinterpret_cast<short*>(&h);
}
// raw v_exp_f32: returns 2^x
__device__ __forceinline__ float fast_exp2(float x) {
  float r;
  asm volatile("v_exp_f32 %0, %1" : "=v"(r) : "v"(x));
  return r;
}
// async global->LDS, 16B per lane. LDS dest = wave-uniform base + lane*16.
__device__ __forceinline__ void gload_lds16(const void* g, void* l) {
  __builtin_amdgcn_global_load_lds(
      (const __attribute__((address_space(1))) unsigned int*)((uintptr_t)g),
      (__attribute__((address_space(3))) unsigned int*)((uintptr_t)l),
      16, 0, 0);
}

// ---------------------------------------------------------------------------
// prep: fused cast(hidden), cast(prev), 4x weight transpose->bf16, rope table,
// pooled partial means (128 blocks, float4). grid 14592, block 256.
__global__ void prep_kernel(const float* __restrict__ hidden, const float* __restrict__ prev,
                            const float* __restrict__ wq, const float* __restrict__ wk,
                            const float* __restrict__ wv, const float* __restrict__ wo,
                            short* __restrict__ hbf, short* __restrict__ pbf,
                            short* __restrict__ wqT, short* __restrict__ wkT,
                            short* __restrict__ wvT, short* __restrict__ woT,
                            float* __restrict__ cost, float* __restrict__ sint,
                            float* __restrict__ pooled) {
  __shared__ short tile[32][33];
  int bid = blockIdx.x, tid = threadIdx.x;
  if (bid < 10240) {  // casts
    const float* src; short* dst; int idx;
    if (bid < 2048) { src = hidden; dst = hbf; idx = bid * 256 + tid; }
    else            { src = prev;   dst = pbf; idx = (bid - 2048) * 256 + tid; }
    const float4* s4 = (const float4*)(src + (size_t)idx * 8);
    float4 a = s4[0], b = s4[1];
    bf16x8 pk;
    pk[0] = f2b(a.x); pk[1] = f2b(a.y); pk[2] = f2b(a.z); pk[3] = f2b(a.w);
    pk[4] = f2b(b.x); pk[5] = f2b(b.y); pk[6] = f2b(b.z); pk[7] = f2b(b.w);
    *(bf16x8*)(dst + (size_t)idx * 8) = pk;
  } else if (bid < 14336) {  // weight transposes
    int tb = bid - 10240;
    int z = tb >> 10, t = tb & 1023;
    const float* src = (z == 0) ? wq : (z == 1) ? wk : (z == 2) ? wv : wo;
    short*       dst = (z == 0) ? wqT : (z == 1) ? wkT : (z == 2) ? wvT : woT;
    int tx = tid & 31, ty = tid >> 5;
    int c0 = (t & 31) * 32, r0 = (t >> 5) * 32;
#pragma unroll
    for (int i = 0; i < 4; ++i)
      tile[ty + 8 * i][tx] = f2b(src[(r0 + ty + 8 * i) * 1024 + c0 + tx]);
    __syncthreads();
#pragma unroll
    for (int i = 0; i < 4; ++i)
      dst[(c0 + ty + 8 * i) * 1024 + r0 + tx] = tile[tx][ty + 8 * i];
  } else if (bid < 14464) {  // rope table
    int idx = (bid - 14336) * 256 + tid;
    int s = idx >> 5, i = idx & 31;
    float invf = expf(-(float)i * (logf(10000.0f) / 32.0f));
    float a = (float)s * invf;
    cost[idx] = cosf(a);
    sint[idx] = sinf(a);
  } else {  // pooled partials: 128 blocks = (b 0..3) x (chunk 0..31), 32 rows each
    int idx = bid - 14464;
    int b = idx >> 5, chunk = idx & 31;
    const float* hp = hidden + (size_t)b * S_ * H_ + (size_t)chunk * 32 * H_ + tid * 4;
    float4 s = {0.f, 0.f, 0.f, 0.f};
#pragma unroll 4
    for (int t = 0; t < 32; ++t) {
      float4 v = *(const float4*)(hp + (size_t)t * H_);
      s.x += v.x; s.y += v.y; s.z += v.z; s.w += v.w;
    }
    float4 r;
    r.x = s.x * (1.0f / 1024.0f); r.y = s.y * (1.0f / 1024.0f);
    r.z = s.z * (1.0f / 1024.0f); r.w = s.w * (1.0f / 1024.0f);
    *(float4*)(pooled + (size_t)(b * 32 + chunk) * 1024 + tid * 4) = r;
  }
}

// ---------------------------------------------------------------------------
// gate: sums the 32 pooled partials per (b,e), then softmax(pooled @ wg).
__global__ void gate_kernel(const float* __restrict__ pooled, const float* __restrict__ wg,
                            float* __restrict__ lw) {
  int w = threadIdx.x >> 6, lane = threadIdx.x & 63;
  float a0 = 0.f, a1 = 0.f, a2 = 0.f, a3 = 0.f;
  for (int e = lane; e < 1024; e += 64) {
    float pv = 0.f;
#pragma unroll
    for (int ch = 0; ch < 32; ++ch) pv += pooled[(size_t)(w * 32 + ch) * 1024 + e];
    a0 += pv * wg[e * 4 + 0];
    a1 += pv * wg[e * 4 + 1];
    a2 += pv * wg[e * 4 + 2];
    a3 += pv * wg[e * 4 + 3];
  }
#pragma unroll
  for (int off = 32; off > 0; off >>= 1) {
    a0 += __shfl_xor(a0, off, 64);
    a1 += __shfl_xor(a1, off, 64);
    a2 += __shfl_xor(a2, off, 64);
    a3 += __shfl_xor(a3, off, 64);
  }
  if (lane == 0) {
    float mx = fmaxf(fmaxf(a0, a1), fmaxf(a2, a3));
    float e0 = expf(a0 - mx), e1 = expf(a1 - mx), e2 = expf(a2 - mx), e3 = expf(a3 - mx);
    float inv = 1.0f / (e0 + e1 + e2 + e3);
    lw[w * 4 + 0] = e0 * inv;
    lw[w * 4 + 1] = e1 * inv;
    lw[w * 4 + 2] = e2 * inv;
    lw[w * 4 + 3] = e3 * inv;
  }
}

// ---------------------------------------------------------------------------
// bias + RoPE epilogue -> [blk*NH+hh][s][64] bf16
__device__ __forceinline__ void rope_epilogue(const f32x4 (&acc)[4][4], const float* __restrict__ bias,
                                              short* __restrict__ outp,
                                              const float* __restrict__ cost,
                                              const float* __restrict__ sint,
                                              int m0, int wm, int quad, int c, int hh) {
  float b0 = bias[hh * 64 + c];
  float b1 = bias[hh * 64 + 16 + c];
  float b2_ = bias[hh * 64 + 32 + c];
  float b3 = bias[hh * 64 + 48 + c];
#pragma unroll
  for (int mt = 0; mt < 4; ++mt) {
    int gm = m0 + wm * 64 + mt * 16 + quad * 4;
#pragma unroll
    for (int j = 0; j < 4; ++j) {
      int m = gm + j;
      int s = m & 1023;
      int bbx = m >> 10;
      int orow = ((bbx * NH + hh) * S_ + s) * HD;
      float c0f = cost[s * 32 + c], s0f = sint[s * 32 + c];
      float x1 = acc[mt][0][j] + b0, x2 = acc[mt][2][j] + b2_;
      outp[orow + c]      = f2b(x1 * c0f - x2 * s0f);
      outp[orow + 32 + c] = f2b(x1 * s0f + x2 * c0f);
      float c1f = cost[s * 32 + 16 + c], s1f = sint[s * 32 + 16 + c];
      float y1 = acc[mt][1][j] + b1, y2 = acc[mt][3][j] + b3;
      outp[orow + 16 + c] = f2b(y1 * c1f - y2 * s1f);
      outp[orow + 48 + c] = f2b(y1 * s1f + y2 * c1f);
    }
  }
}

// ---------------------------------------------------------------------------
// Fused Q+K+V projections, v2: attn-v5-style double-buffered staging with
// counted vmcnt. 128x128 tiles, BK=32, packed LDS (two 32-col m-rows per
// 128B LDS row, XOR-swizzled -> conflict-free, verified chunk algebra).
// Double buffer fits the SAME 48KB as BK=64 single -> 3 blocks/CU kept.
// Per k-step: stage(next) -> vmcnt(6|4) [stage(cur) published, next stays
// in flight] -> barrier -> 12 ds_read + 32 MFMA -> barrier. No vmcnt(0)
// drain in-loop (the m97 ~20% stall). Grid 1280, XCD-coherent decode.
__launch_bounds__(256, 2)
__global__ void qkv_gemm(const short* __restrict__ hbf, const short* __restrict__ pbf,
                         const short* __restrict__ BTq, const short* __restrict__ BTk,
                         const short* __restrict__ BTv,
                         const float* __restrict__ bq, const float* __restrict__ bk,
                         const float* __restrict__ bv,
                         short* __restrict__ outq, short* __restrict__ outk,
                         short* __restrict__ outv,
                         const float* __restrict__ cost, const float* __restrict__ sint) {
  __shared__ __align__(16) short As[2][64 * 64];   // 128 rows x 32 cols packed
  __shared__ __align__(16) short Bs1[2][64 * 64];
  __shared__ __align__(16) short Bs2[2][64 * 64];
  int id = blockIdx.x;
  int xcd = id & 7;
  int local = id >> 3;        // 0..159
  int n0i = local & 7;        // n-block, consecutive per y on one XCD
  int yl = local >> 3;        // 0..19
  int y = yl * 8 + xcd;       // 0..159, y mod 8 == xcd
  int tid = threadIdx.x;
  int lane = tid & 63, wvv = tid >> 6;
  int quad = lane >> 4, c = lane & 15;
  int wm = wvv & 1, wn = wvv >> 1;
  bool isQ = y < 32;
  int m0 = (isQ ? y : (y - 32)) * 128;
  int n0 = n0i * 128;
  const short* A  = isQ ? hbf : pbf;
  const short* B1 = isQ ? BTq : BTk;
  f32x4 acc1[4][4] = {}, acc2[4][4] = {};
  const short* Ab = A + (size_t)m0 * 1024;
  const short* Bb1 = B1 + (size_t)n0 * 1024;
  const short* Bb2 = BTv + (size_t)n0 * 1024;

  // Packed-layout staging addresses. LDS row lr (128B = 8 chunks of 16B)
  // holds m-rows {2lr, 2lr+1} x 32 cols. Stored chunk ch at row lr maps to
  // logical lc = ch ^ (lr&7); m = 2lr + (lc>>2); k-quad = lc&3.
  int lr0 = tid >> 3, ch0 = tid & 7;
  int lr1 = lr0 + 32;
  int lc0 = ch0 ^ (lr0 & 7), lc1 = ch0 ^ (lr1 & 7);
  int am0 = 2 * lr0 + (lc0 >> 2), ak0 = (lc0 & 3) * 8;
  int am1 = 2 * lr1 + (lc1 >> 2), ak1 = (lc1 & 3) * 8;

#define STAGEQKV(bufi, k0s) do {                                             \
    gload_lds16(Ab  + (size_t)am0 * 1024 + (k0s) + ak0, &As[bufi][tid * 8]); \
    gload_lds16(Ab  + (size_t)am1 * 1024 + (k0s) + ak1, &As[bufi][(256 + tid) * 8]); \
    gload_lds16(Bb1 + (size_t)am0 * 1024 + (k0s) + ak0, &Bs1[bufi][tid * 8]); \
    gload_lds16(Bb1 + (size_t)am1 * 1024 + (k0s) + ak1, &Bs1[bufi][(256 + tid) * 8]); \
    if (!isQ) {                                                              \
      gload_lds16(Bb2 + (size_t)am0 * 1024 + (k0s) + ak0, &Bs2[bufi][tid * 8]); \
      gload_lds16(Bb2 + (size_t)am1 * 1024 + (k0s) + ak1, &Bs2[bufi][(256 + tid) * 8]); \
    }                                                                        \
  } while (0)
  // fragment read offset for m-row r, k-quad q (shorts):
#define FRAG_OFF(r, q) (((r) >> 1) * 64 + (((((r) & 1) * 4 + (q)) ^ (((r) >> 1) & 7)) * 8))

  STAGEQKV(0, 0);

  for (int kb = 0; kb < 32; ++kb) {
    int cb = kb & 1;
    if (kb < 31) {
      STAGEQKV(cb ^ 1, (kb + 1) * 32);
      if (isQ) asm volatile("s_waitcnt vmcnt(4)" ::: "memory");
      else     asm volatile("s_waitcnt vmcnt(6)" ::: "memory");
    } else {
      asm volatile("s_waitcnt vmcnt(0)" ::: "memory");
    }
    __builtin_amdgcn_s_barrier();
    __builtin_amdgcn_sched_barrier(0);

    bf16x8 af[4], b1f[4];
#pragma unroll
    for (int mt = 0; mt < 4; ++mt) {
      int r = wm * 64 + mt * 16 + c;
      af[mt] = *(const bf16x8*)&As[cb][FRAG_OFF(r, quad)];
    }
#pragma unroll
    for (int nt = 0; nt < 4; ++nt) {
      int r = wn * 64 + nt * 16 + c;
      b1f[nt] = *(const bf16x8*)&Bs1[cb][FRAG_OFF(r, quad)];
    }
#pragma unroll
    for (int mt = 0; mt < 4; ++mt)
#pragma unroll
      for (int nt = 0; nt < 4; ++nt)
        acc1[mt][nt] = __builtin_amdgcn_mfma_f32_16x16x32_bf16(af[mt], b1f[nt], acc1[mt][nt], 0, 0, 0);
    if (!isQ) {
      bf16x8 b2f_[4];
#pragma unroll
      for (int nt = 0; nt < 4; ++nt) {
        int r = wn * 64 + nt * 16 + c;
        b2f_[nt] = *(const bf16x8*)&Bs2[cb][FRAG_OFF(r, quad)];
      }
#pragma unroll
      for (int mt = 0; mt < 4; ++mt)
#pragma unroll
        for (int nt = 0; nt < 4; ++nt)
          acc2[mt][nt] = __builtin_amdgcn_mfma_f32_16x16x32_bf16(af[mt], b2f_[nt], acc2[mt][nt], 0, 0, 0);
    }
    __builtin_amdgcn_s_barrier();  // consume-done: next iter overwrites buf^1
  }
#undef STAGEQKV
#undef FRAG_OFF

  int colb = n0 + wn * 64;
  int hh = colb >> 6;
  if (isQ) {
    rope_epilogue(acc1, bq, outq, cost, sint, m0, wm, quad, c, hh);
  } else {
    rope_epilogue(acc1, bk, outk, cost, sint, m0, wm, quad, c, hh);
    float bb[4];
#pragma unroll
    for (int nt = 0; nt < 4; ++nt) bb[nt] = bv[hh * 64 + nt * 16 + c];
#pragma unroll
    for (int mt = 0; mt < 4; ++mt) {
      int gm = m0 + wm * 64 + mt * 16 + quad * 4;
      int s4 = gm & 1023, pb = gm >> 10;
#pragma unroll
      for (int nt = 0; nt < 4; ++nt) {
        int d = nt * 16 + c;
        ushort4 pk;
        pk.x = (unsigned short)f2b(acc2[mt][nt][0] + bb[nt]);
        pk.y = (unsigned short)f2b(acc2[mt][nt][1] + bb[nt]);
        pk.z = (unsigned short)f2b(acc2[mt][nt][2] + bb[nt]);
        pk.w = (unsigned short)f2b(acc2[mt][nt][3] + bb[nt]);
        *(ushort4*)&outv[((pb * NH + hh) * HD + d) * S_ + s4] = pk;
      }
    }
  }
}

// ---------------------------------------------------------------------------
// Flash attention v5: 32x32x16 MFMA, S^T = K*Q^T, P fully in registers
// (cvt_pk_bf16 + permlane32_swap). Double-buffered K/V staging with counted
// vmcnt(4) + raw barriers. LDS 33.3KB, 4 blocks/CU.
__launch_bounds__(256, 4)
__global__ void attn_kernel(const short* __restrict__ q, const short* __restrict__ k,
                            const short* __restrict__ vt, short* __restrict__ o) {
  int blk = blockIdx.x;
  int x = blk & 7, qt = (blk >> 3) & 7, g = blk >> 6;
  int pbh = g * 8 + x;
  int b = (pbh >> 4) & 3, h = pbh & 15;
  int tid = threadIdx.x;
  int w = tid >> 6, lane = tid & 63;
  int l31 = lane & 31, hh = lane >> 5;   // half index (lane>=32)
  int r7 = l31 & 7;

  __shared__ __align__(16) short Klds[2][64 * 64];
  __shared__ __align__(16) short Vlds[2][64 * 64];
  __shared__ float lsumf[4][32];

  // Q fragments (B operand of 32x32x16): lane holds Q[q=l31][hd=step*16+hh*8+j]
  const short* qbase = q + ((size_t)(b * NH + h) * S_ + qt * 128 + w * 32 + l31) * HD + hh * 8;
  bf16x8 aq[4];
#pragma unroll
  for (int st4 = 0; st4 < 4; ++st4) aq[st4] = *(const bf16x8*)(qbase + st4 * 16);

  const short* kb = k + (size_t)pbh * S_ * HD;
  const short* vb = vt + (size_t)pbh * HD * S_;

  f32x16 O0 = {}, O1 = {};
  float ls0 = 0.f, ls1 = 0.f, ls2 = 0.f, ls3 = 0.f;
  const float cs = 0.18033688011f;  // 0.125 * log2(e)

  int sr = tid >> 3;
  int lc = (tid & 7) ^ (sr & 7);

#define STAGE_KV(kt2, bufi) do {                                           \
    const short* ksrc = kb + ((kt2) * 64 + sr) * HD + lc * 8;              \
    gload_lds16(ksrc,           &Klds[bufi][tid * 8]);                     \
    gload_lds16(ksrc + 32 * HD, &Klds[bufi][2048 + tid * 8]);              \
    const short* vsrc = vb + (size_t)sr * S_ + (kt2) * 64 + lc * 8;        \
    gload_lds16(vsrc,           &Vlds[bufi][tid * 8]);                     \
    gload_lds16(vsrc + 32 * S_, &Vlds[bufi][2048 + tid * 8]);              \
  } while (0)

  STAGE_KV(0, 0);

  for (int kt = 0; kt < 16; ++kt) {
    int cb = kt & 1;
    if (kt < 15) {
      STAGE_KV(kt + 1, cb ^ 1);
      asm volatile("s_waitcnt vmcnt(4)" ::: "memory");  // publish stage(kt); 4 in flight
    } else {
      asm volatile("s_waitcnt vmcnt(0)" ::: "memory");
    }
    __builtin_amdgcn_s_barrier();
    __builtin_amdgcn_sched_barrier(0);

    // QK^T: two 32x32 k-tiles; contraction over hd=64 in 4 steps of 16.
    // S^T reg layout: q = l31, k32 = (r&3)+8*(r>>2)+4*hh.
    u32x4 pa[4];
#pragma unroll
    for (int tau = 0; tau < 2; ++tau) {
      f32x16 st = {};
#pragma unroll
      for (int step = 0; step < 4; ++step) {
        bf16x8 kf = *(const bf16x8*)&Klds[cb][(tau * 32 + l31) * 64 + (((step * 2 + hh) ^ r7) * 8)];
        st = __builtin_amdgcn_mfma_f32_32x32x16_bf16(kf, aq[step], st, 0, 0, 0);
      }
      unsigned wb[8];
#pragma unroll
      for (int m = 0; m < 8; ++m) {
        float p0 = fast_exp2(st[2 * m] * cs);
        float p1 = fast_exp2(st[2 * m + 1] * cs);
        float ps = p0 + p1;
        if ((m & 3) == 0) ls0 += ps;
        else if ((m & 3) == 1) ls1 += ps;
        else if ((m & 3) == 2) ls2 += ps;
        else ls3 += ps;
        asm("v_cvt_pk_bf16_f32 %0, %1, %2" : "=v"(wb[m]) : "v"(p0), "v"(p1));
      }
#pragma unroll
      for (int gg = 0; gg < 2; ++gg) {
        unsigned x0 = wb[4 * gg + 0], y0 = wb[4 * gg + 2];
        unsigned x1 = wb[4 * gg + 1], y1 = wb[4 * gg + 3];
        asm volatile("v_permlane32_swap_b32 %0, %1" : "+v"(x0), "+v"(y0));
        asm volatile("v_permlane32_swap_b32 %0, %1" : "+v"(x1), "+v"(y1));
        u32x4 paw;
        paw[0] = x0; paw[1] = x1; paw[2] = y0; paw[3] = y1;
        pa[2 * tau + gg] = paw;
      }
    }

    // PV: O[q][d], two 32-wide d-tiles, contraction k=64 in 4 steps of 16.
#pragma unroll
    for (int T = 0; T < 4; ++T) {
      bf16x8 ap = __builtin_bit_cast(bf16x8, pa[T]);
      bf16x8 vf0 = *(const bf16x8*)&Vlds[cb][l31 * 64 + (((T * 2 + hh) ^ r7) * 8)];
      O0 = __builtin_amdgcn_mfma_f32_32x32x16_bf16(ap, vf0, O0, 0, 0, 0);
      bf16x8 vf1 = *(const bf16x8*)&Vlds[cb][(32 + l31) * 64 + (((T * 2 + hh) ^ r7) * 8)];
      O1 = __builtin_amdgcn_mfma_f32_32x32x16_bf16(ap, vf1, O1, 0, 0, 0);
    }

    __builtin_amdgcn_s_barrier();  // consume-done: next iter may overwrite buf^1
  }
#undef STAGE_KV

  float lsum = (ls0 + ls1) + (ls2 + ls3);
  lsum += __shfl_xor(lsum, 32, 64);
  if (lane < 32) lsumf[w][l31] = lsum;

  short* ob = o + ((size_t)pbh * S_ + qt * 128 + w * 32) * HD;
#pragma unroll
  for (int gg = 0; gg < 4; ++gg) {
    f32x4 lv = *(const f32x4*)&lsumf[w][4 * hh + 8 * gg];
#pragma unroll
    for (int j = 0; j < 4; ++j) {
      float inv = 1.0f / lv[j];
      int qrow = 4 * hh + 8 * gg + j;
      ob[qrow * HD + l31]      = f2b(O0[4 * gg + j] * inv);
      ob[qrow * HD + 32 + l31] = f2b(O1[4 * gg + j] * inv);
    }
  }
}

// ---------------------------------------------------------------------------
__global__ void combine_kernel(const short* __restrict__ o, const float* __restrict__ lw,
                               short* __restrict__ comb) {
  int idx = blockIdx.x * 256 + threadIdx.x;
  int e8 = idx & 127;
  int s = (idx >> 7) & 1023;
  int b = idx >> 17;
  int h = e8 >> 3, d0 = (e8 & 7) * 8;
  float acc[8] = {};
#pragma unroll
  for (int p = 0; p < 4; ++p) {
    float wgt = lw[p * 4 + b];  // faithful transposed broadcast: LW[p][b]
    const short* op = o + (((size_t)(p * 4 + b) * NH + h) * S_ + s) * HD + d0;
    bf16x8 v = *(const bf16x8*)op;
#pragma unroll
    for (int i = 0; i < 8; ++i) acc[i] += wgt * b2f(v[i]);
  }
  bf16x8 pk;
#pragma unroll
  for (int i = 0; i < 8; ++i) pk[i] = f2b(acc[i]);
  *(bf16x8*)&comb[((size_t)b * S_ + s) * H_ + e8 * 8] = pk;
}

// ---------------------------------------------------------------------------
// Final projection: C[4096,1024] fp32 = comb @ woT + bo. 64x128 tiles, BK=64,
// swizzled LDS, XCD-coherent decode. grid 512 linear, (256,4).
__launch_bounds__(256, 4)
__global__ void gemm_out(const short* __restrict__ A, const short* __restrict__ BT,
                         const float* __restrict__ bias, float* __restrict__ outf) {
  __shared__ __align__(16) short As[64 * 64];
  __shared__ __align__(16) short Bs[128 * 64];
  int id = blockIdx.x;
  int xcd = id & 7;
  int local = id >> 3;        // 0..63
  int n0i = local & 7;
  int yl = local >> 3;        // 0..7
  int y = yl * 8 + xcd;       // 0..63
  int tid = threadIdx.x;
  int lane = tid & 63, wvv = tid >> 6;
  int quad = lane >> 4, c = lane & 15;
  int wm = wvv & 1, wn = wvv >> 1;
  int m0 = y * 64, n0 = n0i * 128;
  f32x4 acc[2][4] = {};
  const short* Ab = A + (size_t)m0 * 1024;
  const short* Bb = BT + (size_t)n0 * 1024;
  int sr = tid >> 3, sch = tid & 7;

  for (int kb = 0; kb < 16; ++kb) {
    int k0 = kb * 64;
    __syncthreads();
#pragma unroll
    for (int rd = 0; rd < 2; ++rd) {
      int row = sr + rd * 32;
      int col = ((sch ^ (row & 7)) * 8) + k0;
      gload_lds16(Ab + row * 1024 + col, As + rd * 2048 + tid * 8);
    }
#pragma unroll
    for (int rd = 0; rd < 4; ++rd) {
      int row = sr + rd * 32;
      int col = ((sch ^ (row & 7)) * 8) + k0;
      gload_lds16(Bb + row * 1024 + col, Bs + rd * 2048 + tid * 8);
    }
    __syncthreads();
#pragma unroll
    for (int ko = 0; ko < 2; ++ko) {
      bf16x8 af[2], bfr[4];
#pragma unroll
      for (int mt = 0; mt < 2; ++mt) {
        int row = wm * 32 + mt * 16 + c;
        af[mt] = *(const bf16x8*)&As[row * 64 + (((ko * 4 + quad) ^ (row & 7)) * 8)];
      }
#pragma unroll
      for (int nt = 0; nt < 4; ++nt) {
        int row = wn * 64 + nt * 16 + c;
        bfr[nt] = *(const bf16x8*)&Bs[row * 64 + (((ko * 4 + quad) ^ (row & 7)) * 8)];
      }
#pragma unroll
      for (int mt = 0; mt < 2; ++mt)
#pragma unroll
        for (int nt = 0; nt < 4; ++nt)
          acc[mt][nt] = __builtin_amdgcn_mfma_f32_16x16x32_bf16(af[mt], bfr[nt], acc[mt][nt], 0, 0, 0);
    }
  }

  int colb = n0 + wn * 64;
  float bb[4];
#pragma unroll
  for (int nt = 0; nt < 4; ++nt) bb[nt] = bias[colb + nt * 16 + c];
#pragma unroll
  for (int mt = 0; mt < 2; ++mt) {
    int gm = m0 + wm * 32 + mt * 16 + quad * 4;
#pragma unroll
    for (int j = 0; j < 4; ++j) {
      int m = gm + j;
#pragma unroll
      for (int nt = 0; nt < 4; ++nt)
        outf[(size_t)m * 1024 + colb + nt * 16 + c] = acc[mt][nt][j] + bb[nt];
    }
  }
}

// ---------------------------------------------------------------------------
extern "C" void kernel_launch(void* const* d_in, const int* in_sizes, int n_in,
                              void* d_out, int out_size, void* d_ws, size_t ws_size,
                              hipStream_t stream) {
  (void)in_sizes; (void)n_in; (void)out_size; (void)ws_size;
  const float* hidden = (const float*)d_in[0];
  const float* prev   = (const float*)d_in[1];
  const float* wq = (const float*)d_in[2];
  const float* bq = (const float*)d_in[3];
  const float* wk = (const float*)d_in[4];
  const float* bk = (const float*)d_in[5];
  const float* wv = (const float*)d_in[6];
  const float* bv = (const float*)d_in[7];
  const float* wo = (const float*)d_in[8];
  const float* bo = (const float*)d_in[9];
  const float* wg = (const float*)d_in[10];
  float* out = (float*)d_out;
  char* ws = (char*)d_ws;

  size_t off = 0;
  short* wqT = (short*)(ws + off); off += (size_t)1024 * 1024 * 2;
  short* wkT = (short*)(ws + off); off += (size_t)1024 * 1024 * 2;
  short* wvT = (short*)(ws + off); off += (size_t)1024 * 1024 * 2;
  short* woT = (short*)(ws + off); off += (size_t)1024 * 1024 * 2;
  short* hbf = (short*)(ws + off); off += (size_t)B_ * S_ * H_ * 2;
  short* pbf = (short*)(ws + off); off += (size_t)P_ * B_ * S_ * H_ * 2;
  short* qbf = (short*)(ws + off); off += (size_t)B_ * S_ * H_ * 2;
  short* kbf = (short*)(ws + off); off += (size_t)P_ * B_ * S_ * H_ * 2;
  short* vtb = (short*)(ws + off); off += (size_t)P_ * B_ * S_ * H_ * 2;
  float* cost = (float*)(ws + off); off += (size_t)S_ * 32 * 4;
  float* sint = (float*)(ws + off); off += (size_t)S_ * 32 * 4;
  float* pooled = (float*)(ws + off); off += (size_t)B_ * 32 * 1024 * 4;
  float* lw = (float*)(ws + off); off += 64;
  short* obf  = pbf;  // alias: pbf dead after QKV proj
  short* comb = qbf;  // alias: qbf dead after attention

  prep_kernel<<<14592, 256, 0, stream>>>(hidden, prev, wq, wk, wv, wo,
                                         hbf, pbf, wqT, wkT, wvT, woT,
                                         cost, sint, pooled);
  gate_kernel<<<1, 256, 0, stream>>>(pooled, wg, lw);
  qkv_gemm<<<1280, 256, 0, stream>>>(hbf, pbf, wqT, wkT, wvT,
                                     bq, bk, bv, qbf, kbf, vtb, cost, sint);
  attn_kernel<<<2048, 256, 0, stream>>>(qbf, kbf, vtb, obf);
  combine_kernel<<<2048, 256, 0, stream>>>(obf, lw, comb);
  gemm_out<<<512, 256, 0, stream>>>(comb, woT, bo, out);
}

// Round 7
// 332.736 us; speedup vs baseline: 1.0690x; 1.0690x over previous
//
#include <hip/hip_runtime.h>
#include <hip/hip_bf16.h>

// Problem constants
#define B_  4
#define S_  1024
#define H_  1024
#define NH  16
#define HD  64
#define P_  4

typedef __attribute__((ext_vector_type(8))) short bf16x8;
typedef __attribute__((ext_vector_type(4))) float f32x4;
typedef __attribute__((ext_vector_type(16))) float f32x16;
typedef __attribute__((ext_vector_type(4))) unsigned int u32x4;

__device__ __forceinline__ float b2f(short s) {
  union { unsigned int u; float f; } v;
  v.u = ((unsigned int)(unsigned short)s) << 16;
  return v.f;
}
__device__ __forceinline__ short f2b(float f) {
  __hip_bfloat16 h = __float2bfloat16(f);
  return *reinterpret_cast<short*>(&h);
}
// raw v_exp_f32: returns 2^x
__device__ __forceinline__ float fast_exp2(float x) {
  float r;
  asm volatile("v_exp_f32 %0, %1" : "=v"(r) : "v"(x));
  return r;
}
// async global->LDS, 16B per lane. LDS dest = wave-uniform base + lane*16.
__device__ __forceinline__ void gload_lds16(const void* g, void* l) {
  __builtin_amdgcn_global_load_lds(
      (const __attribute__((address_space(1))) unsigned int*)((uintptr_t)g),
      (__attribute__((address_space(3))) unsigned int*)((uintptr_t)l),
      16, 0, 0);
}

// ---------------------------------------------------------------------------
// prep: fused cast(hidden), cast(prev), 4x weight transpose->bf16, rope table,
// pooled partial means (128 blocks, float4). grid 14592, block 256.
__global__ void prep_kernel(const float* __restrict__ hidden, const float* __restrict__ prev,
                            const float* __restrict__ wq, const float* __restrict__ wk,
                            const float* __restrict__ wv, const float* __restrict__ wo,
                            short* __restrict__ hbf, short* __restrict__ pbf,
                            short* __restrict__ wqT, short* __restrict__ wkT,
                            short* __restrict__ wvT, short* __restrict__ woT,
                            float* __restrict__ cost, float* __restrict__ sint,
                            float* __restrict__ pooled) {
  __shared__ short tile[32][33];
  int bid = blockIdx.x, tid = threadIdx.x;
  if (bid < 10240) {  // casts
    const float* src; short* dst; int idx;
    if (bid < 2048) { src = hidden; dst = hbf; idx = bid * 256 + tid; }
    else            { src = prev;   dst = pbf; idx = (bid - 2048) * 256 + tid; }
    const float4* s4 = (const float4*)(src + (size_t)idx * 8);
    float4 a = s4[0], b = s4[1];
    bf16x8 pk;
    pk[0] = f2b(a.x); pk[1] = f2b(a.y); pk[2] = f2b(a.z); pk[3] = f2b(a.w);
    pk[4] = f2b(b.x); pk[5] = f2b(b.y); pk[6] = f2b(b.z); pk[7] = f2b(b.w);
    *(bf16x8*)(dst + (size_t)idx * 8) = pk;
  } else if (bid < 14336) {  // weight transposes
    int tb = bid - 10240;
    int z = tb >> 10, t = tb & 1023;
    const float* src = (z == 0) ? wq : (z == 1) ? wk : (z == 2) ? wv : wo;
    short*       dst = (z == 0) ? wqT : (z == 1) ? wkT : (z == 2) ? wvT : woT;
    int tx = tid & 31, ty = tid >> 5;
    int c0 = (t & 31) * 32, r0 = (t >> 5) * 32;
#pragma unroll
    for (int i = 0; i < 4; ++i)
      tile[ty + 8 * i][tx] = f2b(src[(r0 + ty + 8 * i) * 1024 + c0 + tx]);
    __syncthreads();
#pragma unroll
    for (int i = 0; i < 4; ++i)
      dst[(c0 + ty + 8 * i) * 1024 + r0 + tx] = tile[tx][ty + 8 * i];
  } else if (bid < 14464) {  // rope table
    int idx = (bid - 14336) * 256 + tid;
    int s = idx >> 5, i = idx & 31;
    float invf = expf(-(float)i * (logf(10000.0f) / 32.0f));
    float a = (float)s * invf;
    cost[idx] = cosf(a);
    sint[idx] = sinf(a);
  } else {  // pooled partials: 128 blocks = (b 0..3) x (chunk 0..31), 32 rows each
    int idx = bid - 14464;
    int b = idx >> 5, chunk = idx & 31;
    const float* hp = hidden + (size_t)b * S_ * H_ + (size_t)chunk * 32 * H_ + tid * 4;
    float4 s = {0.f, 0.f, 0.f, 0.f};
#pragma unroll 4
    for (int t = 0; t < 32; ++t) {
      float4 v = *(const float4*)(hp + (size_t)t * H_);
      s.x += v.x; s.y += v.y; s.z += v.z; s.w += v.w;
    }
    float4 r;
    r.x = s.x * (1.0f / 1024.0f); r.y = s.y * (1.0f / 1024.0f);
    r.z = s.z * (1.0f / 1024.0f); r.w = s.w * (1.0f / 1024.0f);
    *(float4*)(pooled + (size_t)(b * 32 + chunk) * 1024 + tid * 4) = r;
  }
}

// ---------------------------------------------------------------------------
// gate v2: grid 4 (one block per batch). Sums 32 pooled partials per e,
// dots with wg, block-reduces, softmax -> lw[b*4 + j].
__global__ void gate_kernel(const float* __restrict__ pooled, const float* __restrict__ wg,
                            float* __restrict__ lw) {
  __shared__ float red[4][4];
  int b = blockIdx.x, tid = threadIdx.x;
  int w = tid >> 6, lane = tid & 63;
  int e0 = tid * 4;
  float4 pv = {0.f, 0.f, 0.f, 0.f};
#pragma unroll 4
  for (int ch = 0; ch < 32; ++ch) {
    float4 v = *(const float4*)&pooled[(size_t)(b * 32 + ch) * 1024 + e0];
    pv.x += v.x; pv.y += v.y; pv.z += v.z; pv.w += v.w;
  }
  float a[4];
#pragma unroll
  for (int j = 0; j < 4; ++j)
    a[j] = pv.x * wg[(e0 + 0) * 4 + j] + pv.y * wg[(e0 + 1) * 4 + j] +
           pv.z * wg[(e0 + 2) * 4 + j] + pv.w * wg[(e0 + 3) * 4 + j];
#pragma unroll
  for (int off = 32; off > 0; off >>= 1)
#pragma unroll
    for (int j = 0; j < 4; ++j) a[j] += __shfl_xor(a[j], off, 64);
  if (lane == 0) {
    red[w][0] = a[0]; red[w][1] = a[1]; red[w][2] = a[2]; red[w][3] = a[3];
  }
  __syncthreads();
  if (tid == 0) {
    float s0 = red[0][0] + red[1][0] + red[2][0] + red[3][0];
    float s1 = red[0][1] + red[1][1] + red[2][1] + red[3][1];
    float s2 = red[0][2] + red[1][2] + red[2][2] + red[3][2];
    float s3 = red[0][3] + red[1][3] + red[2][3] + red[3][3];
    float mx = fmaxf(fmaxf(s0, s1), fmaxf(s2, s3));
    float e0_ = expf(s0 - mx), e1 = expf(s1 - mx), e2 = expf(s2 - mx), e3 = expf(s3 - mx);
    float inv = 1.0f / (e0_ + e1 + e2 + e3);
    lw[b * 4 + 0] = e0_ * inv;
    lw[b * 4 + 1] = e1 * inv;
    lw[b * 4 + 2] = e2 * inv;
    lw[b * 4 + 3] = e3 * inv;
  }
}

// ---------------------------------------------------------------------------
// bias + RoPE epilogue -> [blk*NH+hh][s][64] bf16
__device__ __forceinline__ void rope_epilogue(const f32x4 (&acc)[4][4], const float* __restrict__ bias,
                                              short* __restrict__ outp,
                                              const float* __restrict__ cost,
                                              const float* __restrict__ sint,
                                              int m0, int wm, int quad, int c, int hh) {
  float b0 = bias[hh * 64 + c];
  float b1 = bias[hh * 64 + 16 + c];
  float b2_ = bias[hh * 64 + 32 + c];
  float b3 = bias[hh * 64 + 48 + c];
#pragma unroll
  for (int mt = 0; mt < 4; ++mt) {
    int gm = m0 + wm * 64 + mt * 16 + quad * 4;
#pragma unroll
    for (int j = 0; j < 4; ++j) {
      int m = gm + j;
      int s = m & 1023;
      int bbx = m >> 10;
      int orow = ((bbx * NH + hh) * S_ + s) * HD;
      float c0f = cost[s * 32 + c], s0f = sint[s * 32 + c];
      float x1 = acc[mt][0][j] + b0, x2 = acc[mt][2][j] + b2_;
      outp[orow + c]      = f2b(x1 * c0f - x2 * s0f);
      outp[orow + 32 + c] = f2b(x1 * s0f + x2 * c0f);
      float c1f = cost[s * 32 + 16 + c], s1f = sint[s * 32 + 16 + c];
      float y1 = acc[mt][1][j] + b1, y2 = acc[mt][3][j] + b3;
      outp[orow + 16 + c] = f2b(y1 * c1f - y2 * s1f);
      outp[orow + 48 + c] = f2b(y1 * s1f + y2 * c1f);
    }
  }
}

// ---------------------------------------------------------------------------
// Fused Q+K+V projections (round-4 known-good, 91us). Linear grid 1280;
// 128x128 tiles, BK=64, XOR-swizzled LDS, XCD-coherent decode.
__launch_bounds__(256, 2)
__global__ void qkv_gemm(const short* __restrict__ hbf, const short* __restrict__ pbf,
                         const short* __restrict__ BTq, const short* __restrict__ BTk,
                         const short* __restrict__ BTv,
                         const float* __restrict__ bq, const float* __restrict__ bk,
                         const float* __restrict__ bv,
                         short* __restrict__ outq, short* __restrict__ outk,
                         short* __restrict__ outv,
                         const float* __restrict__ cost, const float* __restrict__ sint) {
  __shared__ __align__(16) short As[128 * 64];
  __shared__ __align__(16) short Bs1[128 * 64];
  __shared__ __align__(16) short Bs2[128 * 64];
  int id = blockIdx.x;
  int xcd = id & 7;
  int local = id >> 3;        // 0..159
  int n0i = local & 7;        // n-block, consecutive per y on one XCD
  int yl = local >> 3;        // 0..19
  int y = yl * 8 + xcd;       // 0..159, y mod 8 == xcd
  int tid = threadIdx.x;
  int lane = tid & 63, wvv = tid >> 6;
  int quad = lane >> 4, c = lane & 15;
  int wm = wvv & 1, wn = wvv >> 1;
  bool isQ = y < 32;
  int m0 = (isQ ? y : (y - 32)) * 128;
  int n0 = n0i * 128;
  const short* A  = isQ ? hbf : pbf;
  const short* B1 = isQ ? BTq : BTk;
  f32x4 acc1[4][4] = {}, acc2[4][4] = {};
  const short* Ab = A + (size_t)m0 * 1024;
  const short* Bb1 = B1 + (size_t)n0 * 1024;
  const short* Bb2 = BTv + (size_t)n0 * 1024;
  int sr = tid >> 3, sch = tid & 7;

  for (int kb = 0; kb < 16; ++kb) {
    int k0 = kb * 64;
    __syncthreads();
#pragma unroll
    for (int rd = 0; rd < 4; ++rd) {
      int row = sr + rd * 32;
      int col = ((sch ^ (row & 7)) * 8) + k0;
      gload_lds16(Ab + row * 1024 + col,  As  + rd * 2048 + tid * 8);
      gload_lds16(Bb1 + row * 1024 + col, Bs1 + rd * 2048 + tid * 8);
      if (!isQ) gload_lds16(Bb2 + row * 1024 + col, Bs2 + rd * 2048 + tid * 8);
    }
    __syncthreads();
#pragma unroll
    for (int ko = 0; ko < 2; ++ko) {
      bf16x8 af[4], b1f[4];
#pragma unroll
      for (int mt = 0; mt < 4; ++mt) {
        int row = wm * 64 + mt * 16 + c;
        af[mt] = *(const bf16x8*)&As[row * 64 + (((ko * 4 + quad) ^ (row & 7)) * 8)];
      }
#pragma unroll
      for (int nt = 0; nt < 4; ++nt) {
        int row = wn * 64 + nt * 16 + c;
        b1f[nt] = *(const bf16x8*)&Bs1[row * 64 + (((ko * 4 + quad) ^ (row & 7)) * 8)];
      }
#pragma unroll
      for (int mt = 0; mt < 4; ++mt)
#pragma unroll
        for (int nt = 0; nt < 4; ++nt)
          acc1[mt][nt] = __builtin_amdgcn_mfma_f32_16x16x32_bf16(af[mt], b1f[nt], acc1[mt][nt], 0, 0, 0);
      if (!isQ) {
        bf16x8 b2f_[4];
#pragma unroll
        for (int nt = 0; nt < 4; ++nt) {
          int row = wn * 64 + nt * 16 + c;
          b2f_[nt] = *(const bf16x8*)&Bs2[row * 64 + (((ko * 4 + quad) ^ (row & 7)) * 8)];
        }
#pragma unroll
        for (int mt = 0; mt < 4; ++mt)
#pragma unroll
          for (int nt = 0; nt < 4; ++nt)
            acc2[mt][nt] = __builtin_amdgcn_mfma_f32_16x16x32_bf16(af[mt], b2f_[nt], acc2[mt][nt], 0, 0, 0);
      }
    }
  }

  int colb = n0 + wn * 64;
  int hh = colb >> 6;
  if (isQ) {
    rope_epilogue(acc1, bq, outq, cost, sint, m0, wm, quad, c, hh);
  } else {
    rope_epilogue(acc1, bk, outk, cost, sint, m0, wm, quad, c, hh);
    float bb[4];
#pragma unroll
    for (int nt = 0; nt < 4; ++nt) bb[nt] = bv[hh * 64 + nt * 16 + c];
#pragma unroll
    for (int mt = 0; mt < 4; ++mt) {
      int gm = m0 + wm * 64 + mt * 16 + quad * 4;
      int s4 = gm & 1023, pb = gm >> 10;
#pragma unroll
      for (int nt = 0; nt < 4; ++nt) {
        int d = nt * 16 + c;
        ushort4 pk;
        pk.x = (unsigned short)f2b(acc2[mt][nt][0] + bb[nt]);
        pk.y = (unsigned short)f2b(acc2[mt][nt][1] + bb[nt]);
        pk.z = (unsigned short)f2b(acc2[mt][nt][2] + bb[nt]);
        pk.w = (unsigned short)f2b(acc2[mt][nt][3] + bb[nt]);
        *(ushort4*)&outv[((pb * NH + hh) * HD + d) * S_ + s4] = pk;
      }
    }
  }
}

// ---------------------------------------------------------------------------
// Flash attention v6: FUSED layer-combine. One block owns (b,h,qt); loops
// p=0..3 through the same double-buffered K/V pipeline (Q shared across p),
// normalizes each O_p by its row-sum and accumulates C += lw[p][b]*O_p/lsum
// in registers; writes comb [b][s][h*64+d] bf16 directly. Eliminates the
// combine kernel, the obf write (32MB) and its re-read (33MB).
// grid 512 (all resident at 2 blocks/CU), block 256, LDS 33.3KB.
__launch_bounds__(256, 2)
__global__ void attn_kernel(const short* __restrict__ q, const short* __restrict__ k,
                            const short* __restrict__ vt, const float* __restrict__ lw,
                            short* __restrict__ comb) {
  int blk = blockIdx.x;
  int x = blk & 7, qt = (blk >> 3) & 7, g = blk >> 6;   // g 0..7
  int bh = g * 8 + x;               // 0..63, same-bh blocks share an XCD
  int b = bh >> 4, h = bh & 15;
  int tid = threadIdx.x;
  int w = tid >> 6, lane = tid & 63;
  int l31 = lane & 31, hh = lane >> 5;   // half index (lane>=32)
  int r7 = l31 & 7;

  __shared__ __align__(16) short Klds[2][64 * 64];
  __shared__ __align__(16) short Vlds[2][64 * 64];
  __shared__ float lsumf[4][32];

  // Q fragments (B operand of 32x32x16): lane holds Q[q=l31][hd=step*16+hh*8+j]
  const short* qbase = q + ((size_t)(b * NH + h) * S_ + qt * 128 + w * 32 + l31) * HD + hh * 8;
  bf16x8 aq[4];
#pragma unroll
  for (int st4 = 0; st4 < 4; ++st4) aq[st4] = *(const bf16x8*)(qbase + st4 * 16);

  // layer-gate weights (block-uniform addresses; hoisted like aq)
  float wl0 = lw[b], wl1 = lw[4 + b], wl2 = lw[8 + b], wl3 = lw[12 + b];

  const short* kbase = k + (size_t)(b * 16 + h) * S_ * HD;
  const short* vbase = vt + (size_t)(b * 16 + h) * HD * S_;
  const size_t pstr = (size_t)64 * S_ * HD;   // p-stride in shorts

  f32x16 C0 = {}, C1 = {};
  const float cs = 0.18033688011f;  // 0.125 * log2(e)

  int sr = tid >> 3;
  int lc = (tid & 7) ^ (sr & 7);

#define STAGE_KV(kb2, vb2, kt2, bufi) do {                                 \
    const short* ksrc = (kb2) + ((kt2) * 64 + sr) * HD + lc * 8;           \
    gload_lds16(ksrc,           &Klds[bufi][tid * 8]);                     \
    gload_lds16(ksrc + 32 * HD, &Klds[bufi][2048 + tid * 8]);              \
    const short* vsrc = (vb2) + (size_t)sr * S_ + (kt2) * 64 + lc * 8;     \
    gload_lds16(vsrc,           &Vlds[bufi][tid * 8]);                     \
    gload_lds16(vsrc + 32 * S_, &Vlds[bufi][2048 + tid * 8]);              \
  } while (0)

  STAGE_KV(kbase, vbase, 0, 0);

#pragma unroll 1
  for (int p = 0; p < 4; ++p) {
    f32x16 O0 = {}, O1 = {};
    float ls0 = 0.f, ls1 = 0.f, ls2 = 0.f, ls3 = 0.f;

#pragma unroll 1
    for (int kt = 0; kt < 16; ++kt) {
      int t = p * 16 + kt;
      int cb = t & 1;
      if (t < 63) {
        int t1 = t + 1;
        int p2 = t1 >> 4, kt2 = t1 & 15;
        const short* kb2 = kbase + (size_t)p2 * pstr;
        const short* vb2 = vbase + (size_t)p2 * pstr;
        STAGE_KV(kb2, vb2, kt2, cb ^ 1);
        asm volatile("s_waitcnt vmcnt(4)" ::: "memory");  // publish stage(t)
      } else {
        asm volatile("s_waitcnt vmcnt(0)" ::: "memory");
      }
      __builtin_amdgcn_s_barrier();
      __builtin_amdgcn_sched_barrier(0);

      // QK^T: two 32x32 k-tiles; contraction over hd=64 in 4 steps of 16.
      // S^T reg layout: q = l31, k32 = (r&3)+8*(r>>2)+4*hh.
      u32x4 pa[4];
#pragma unroll
      for (int tau = 0; tau < 2; ++tau) {
        f32x16 st = {};
#pragma unroll
        for (int step = 0; step < 4; ++step) {
          bf16x8 kf = *(const bf16x8*)&Klds[cb][(tau * 32 + l31) * 64 + (((step * 2 + hh) ^ r7) * 8)];
          st = __builtin_amdgcn_mfma_f32_32x32x16_bf16(kf, aq[step], st, 0, 0, 0);
        }
        unsigned wb[8];
#pragma unroll
        for (int m = 0; m < 8; ++m) {
          float p0 = fast_exp2(st[2 * m] * cs);
          float p1 = fast_exp2(st[2 * m + 1] * cs);
          float ps = p0 + p1;
          if ((m & 3) == 0) ls0 += ps;
          else if ((m & 3) == 1) ls1 += ps;
          else if ((m & 3) == 2) ls2 += ps;
          else ls3 += ps;
          asm("v_cvt_pk_bf16_f32 %0, %1, %2" : "=v"(wb[m]) : "v"(p0), "v"(p1));
        }
#pragma unroll
        for (int gg = 0; gg < 2; ++gg) {
          unsigned x0 = wb[4 * gg + 0], y0 = wb[4 * gg + 2];
          unsigned x1 = wb[4 * gg + 1], y1 = wb[4 * gg + 3];
          asm volatile("v_permlane32_swap_b32 %0, %1" : "+v"(x0), "+v"(y0));
          asm volatile("v_permlane32_swap_b32 %0, %1" : "+v"(x1), "+v"(y1));
          u32x4 paw;
          paw[0] = x0; paw[1] = x1; paw[2] = y0; paw[3] = y1;
          pa[2 * tau + gg] = paw;
        }
      }

      // PV: O[q][d], two 32-wide d-tiles, contraction k=64 in 4 steps of 16.
#pragma unroll
      for (int T = 0; T < 4; ++T) {
        bf16x8 ap = __builtin_bit_cast(bf16x8, pa[T]);
        bf16x8 vf0 = *(const bf16x8*)&Vlds[cb][l31 * 64 + (((T * 2 + hh) ^ r7) * 8)];
        O0 = __builtin_amdgcn_mfma_f32_32x32x16_bf16(ap, vf0, O0, 0, 0, 0);
        bf16x8 vf1 = *(const bf16x8*)&Vlds[cb][(32 + l31) * 64 + (((T * 2 + hh) ^ r7) * 8)];
        O1 = __builtin_amdgcn_mfma_f32_32x32x16_bf16(ap, vf1, O1, 0, 0, 0);
      }

      __builtin_amdgcn_s_barrier();  // consume-done: next iter overwrites buf^1
    }

    // finalize p: row-sum, normalize, gate-weight, accumulate into C.
    float lsum = (ls0 + ls1) + (ls2 + ls3);
    lsum += __shfl_xor(lsum, 32, 64);
    if (lane < 32) lsumf[w][l31] = lsum;   // per-wave row, same-wave read below
    float wl = (p == 0) ? wl0 : (p == 1) ? wl1 : (p == 2) ? wl2 : wl3;
#pragma unroll
    for (int gg = 0; gg < 4; ++gg) {
      f32x4 lv = *(const f32x4*)&lsumf[w][4 * hh + 8 * gg];
#pragma unroll
      for (int j = 0; j < 4; ++j) {
        float sc = wl / lv[j];
        C0[4 * gg + j] += O0[4 * gg + j] * sc;
        C1[4 * gg + j] += O1[4 * gg + j] * sc;
      }
    }
  }
#undef STAGE_KV

  // Epilogue: comb[b][s][h*64+d], reg r=4*gg+j -> qrow = 4*hh+8*gg+j, d = dt*32+l31.
  short* ob = comb + ((size_t)b * S_ + qt * 128 + w * 32) * H_ + h * 64;
#pragma unroll
  for (int gg = 0; gg < 4; ++gg) {
#pragma unroll
    for (int j = 0; j < 4; ++j) {
      int qrow = 4 * hh + 8 * gg + j;
      ob[(size_t)qrow * H_ + l31]      = f2b(C0[4 * gg + j]);
      ob[(size_t)qrow * H_ + 32 + l31] = f2b(C1[4 * gg + j]);
    }
  }
}

// ---------------------------------------------------------------------------
// Final projection: C[4096,1024] fp32 = comb @ woT + bo. 64x128 tiles, BK=64,
// swizzled LDS, XCD-coherent decode. grid 512 linear, (256,4).
__launch_bounds__(256, 4)
__global__ void gemm_out(const short* __restrict__ A, const short* __restrict__ BT,
                         const float* __restrict__ bias, float* __restrict__ outf) {
  __shared__ __align__(16) short As[64 * 64];
  __shared__ __align__(16) short Bs[128 * 64];
  int id = blockIdx.x;
  int xcd = id & 7;
  int local = id >> 3;        // 0..63
  int n0i = local & 7;
  int yl = local >> 3;        // 0..7
  int y = yl * 8 + xcd;       // 0..63
  int tid = threadIdx.x;
  int lane = tid & 63, wvv = tid >> 6;
  int quad = lane >> 4, c = lane & 15;
  int wm = wvv & 1, wn = wvv >> 1;
  int m0 = y * 64, n0 = n0i * 128;
  f32x4 acc[2][4] = {};
  const short* Ab = A + (size_t)m0 * 1024;
  const short* Bb = BT + (size_t)n0 * 1024;
  int sr = tid >> 3, sch = tid & 7;

  for (int kb = 0; kb < 16; ++kb) {
    int k0 = kb * 64;
    __syncthreads();
#pragma unroll
    for (int rd = 0; rd < 2; ++rd) {
      int row = sr + rd * 32;
      int col = ((sch ^ (row & 7)) * 8) + k0;
      gload_lds16(Ab + row * 1024 + col, As + rd * 2048 + tid * 8);
    }
#pragma unroll
    for (int rd = 0; rd < 4; ++rd) {
      int row = sr + rd * 32;
      int col = ((sch ^ (row & 7)) * 8) + k0;
      gload_lds16(Bb + row * 1024 + col, Bs + rd * 2048 + tid * 8);
    }
    __syncthreads();
#pragma unroll
    for (int ko = 0; ko < 2; ++ko) {
      bf16x8 af[2], bfr[4];
#pragma unroll
      for (int mt = 0; mt < 2; ++mt) {
        int row = wm * 32 + mt * 16 + c;
        af[mt] = *(const bf16x8*)&As[row * 64 + (((ko * 4 + quad) ^ (row & 7)) * 8)];
      }
#pragma unroll
      for (int nt = 0; nt < 4; ++nt) {
        int row = wn * 64 + nt * 16 + c;
        bfr[nt] = *(const bf16x8*)&Bs[row * 64 + (((ko * 4 + quad) ^ (row & 7)) * 8)];
      }
#pragma unroll
      for (int mt = 0; mt < 2; ++mt)
#pragma unroll
        for (int nt = 0; nt < 4; ++nt)
          acc[mt][nt] = __builtin_amdgcn_mfma_f32_16x16x32_bf16(af[mt], bfr[nt], acc[mt][nt], 0, 0, 0);
    }
  }

  int colb = n0 + wn * 64;
  float bb[4];
#pragma unroll
  for (int nt = 0; nt < 4; ++nt) bb[nt] = bias[colb + nt * 16 + c];
#pragma unroll
  for (int mt = 0; mt < 2; ++mt) {
    int gm = m0 + wm * 32 + mt * 16 + quad * 4;
#pragma unroll
    for (int j = 0; j < 4; ++j) {
      int m = gm + j;
#pragma unroll
      for (int nt = 0; nt < 4; ++nt)
        outf[(size_t)m * 1024 + colb + nt * 16 + c] = acc[mt][nt][j] + bb[nt];
    }
  }
}

// ---------------------------------------------------------------------------
extern "C" void kernel_launch(void* const* d_in, const int* in_sizes, int n_in,
                              void* d_out, int out_size, void* d_ws, size_t ws_size,
                              hipStream_t stream) {
  (void)in_sizes; (void)n_in; (void)out_size; (void)ws_size;
  const float* hidden = (const float*)d_in[0];
  const float* prev   = (const float*)d_in[1];
  const float* wq = (const float*)d_in[2];
  const float* bq = (const float*)d_in[3];
  const float* wk = (const float*)d_in[4];
  const float* bk = (const float*)d_in[5];
  const float* wv = (const float*)d_in[6];
  const float* bv = (const float*)d_in[7];
  const float* wo = (const float*)d_in[8];
  const float* bo = (const float*)d_in[9];
  const float* wg = (const float*)d_in[10];
  float* out = (float*)d_out;
  char* ws = (char*)d_ws;

  size_t off = 0;
  short* wqT = (short*)(ws + off); off += (size_t)1024 * 1024 * 2;
  short* wkT = (short*)(ws + off); off += (size_t)1024 * 1024 * 2;
  short* wvT = (short*)(ws + off); off += (size_t)1024 * 1024 * 2;
  short* woT = (short*)(ws + off); off += (size_t)1024 * 1024 * 2;
  short* hbf = (short*)(ws + off); off += (size_t)B_ * S_ * H_ * 2;
  short* pbf = (short*)(ws + off); off += (size_t)P_ * B_ * S_ * H_ * 2;
  short* qbf = (short*)(ws + off); off += (size_t)B_ * S_ * H_ * 2;
  short* kbf = (short*)(ws + off); off += (size_t)P_ * B_ * S_ * H_ * 2;
  short* vtb = (short*)(ws + off); off += (size_t)P_ * B_ * S_ * H_ * 2;
  float* cost = (float*)(ws + off); off += (size_t)S_ * 32 * 4;
  float* sint = (float*)(ws + off); off += (size_t)S_ * 32 * 4;
  float* pooled = (float*)(ws + off); off += (size_t)B_ * 32 * 1024 * 4;
  float* lw = (float*)(ws + off); off += 64;
  short* comb = pbf;  // alias: pbf dead after QKV proj (attn reads qbf/kbf/vtb)

  prep_kernel<<<14592, 256, 0, stream>>>(hidden, prev, wq, wk, wv, wo,
                                         hbf, pbf, wqT, wkT, wvT, woT,
                                         cost, sint, pooled);
  gate_kernel<<<4, 256, 0, stream>>>(pooled, wg, lw);
  qkv_gemm<<<1280, 256, 0, stream>>>(hbf, pbf, wqT, wkT, wvT,
                                     bq, bk, bv, qbf, kbf, vtb, cost, sint);
  attn_kernel<<<512, 256, 0, stream>>>(qbf, kbf, vtb, lw, comb);
  gemm_out<<<512, 256, 0, stream>>>(comb, woT, bo, out);
}